// Round 1
// baseline (514.342 us; speedup 1.0000x reference)
//
#include <hip/hip_runtime.h>
#include <stdint.h>

// LNSLinear inference: out[m,n] = sign(S[m,n]) * P[m,n] + bias[n]
//   P = |x| @ |w|^T (bf16), S = sign(x) @ sign(w)^T (exact, +-1 bf16)
// M = 262144, N = 256, K = 256.
// v2: B (Wp, 256KB, L2-hot) loaded direct global->reg (no sB LDS);
//     A staged via global_load_lds into 4-deep LDS ring (prefetch ~2 iters);
//     one raw s_barrier per k-iter, no vmcnt(0) in main loop;
//     sign extraction via v_perm_b32 (3 VALU per 2 elements).

#define K_DIM 256
#define N_DIM 256
#define BM 128
#define BN 128
#define BK 32
#define NKBLK 8  // K_DIM / BK

typedef float f32x4 __attribute__((ext_vector_type(4)));
typedef __bf16 bf16x8 __attribute__((ext_vector_type(8)));
typedef unsigned short u16x4v __attribute__((ext_vector_type(4)));
typedef unsigned short u16x8v __attribute__((ext_vector_type(8)));
typedef unsigned int u32x4v __attribute__((ext_vector_type(4)));

// ---------- pre-kernel: W fp32 [N][K] -> ws bf16 rows [(n*8+kblk)][abs 32 | sgn 32] ----------
__global__ void w_convert_kernel(const float* __restrict__ W, unsigned short* __restrict__ Wp) {
    int t = blockIdx.x * 256 + threadIdx.x;  // 0..16383, each handles 4 k
    int n = t >> 6;
    int k = (t & 63) << 2;
    float4 v = *(const float4*)(W + (size_t)n * K_DIM + k);
    unsigned short* row = Wp + ((size_t)n * NKBLK + (k >> 5)) * 64;
    int pos = k & 31;
    float vv[4] = {v.x, v.y, v.z, v.w};
    u16x4v a, s;
#pragma unroll
    for (int j = 0; j < 4; ++j) {
        __bf16 h = (__bf16)__builtin_fabsf(vv[j]);
        a[j] = __builtin_bit_cast(unsigned short, h);
        unsigned int u = __float_as_uint(vv[j]);
        s[j] = (unsigned short)(0x3F80u | ((u >> 16) & 0x8000u));
    }
    *(u16x4v*)(row + pos) = a;
    *(u16x4v*)(row + 32 + pos) = s;
}

__device__ __forceinline__ void gload_lds16(const void* g, void* l) {
    __builtin_amdgcn_global_load_lds(
        (const __attribute__((address_space(1))) unsigned int*)g,
        (__attribute__((address_space(3))) unsigned int*)l, 16, 0, 0);
}

// Pack signs of two floats into one u32 of two bf16 (+1.0 / -1.0):
// byte1 = top byte of lo, byte3 = top byte of hi; keep sign bits; OR in 1.0f bf16.
__device__ __forceinline__ unsigned int sgnpk(float hi, float lo) {
    return (__builtin_amdgcn_perm(__float_as_uint(hi), __float_as_uint(lo), 0x07000300u)
            & 0x80008000u) | 0x3F803F80u;
}

// ---------- main kernel ----------
__global__ __launch_bounds__(256, 2)
void lns_gemm_kernel(const float* __restrict__ X, const unsigned short* __restrict__ Wp,
                     const float* __restrict__ bias, float* __restrict__ out) {
    // A ring: [4 buf][128 rows][32 fp32] (row = 128 B = 8 chunks, XOR-swizzled)
    __shared__ __attribute__((aligned(16))) float sA[4][BM * BK];

    const int tid  = threadIdx.x;
    const int lane = tid & 63;
    const int wave = tid >> 6;
    const int quad = lane >> 4;
    const int l16  = lane & 15;
    const int mb   = blockIdx.y;
    const int nb   = blockIdx.x;
    const int wm   = (wave >> 1) * 64;
    const int wn   = (wave & 1) * 64;

    const float* Ax = X + (size_t)(mb * BM) * K_DIM;

    // Per-thread A staging source pointers (fixed; k-iter advance folds to imm offsets).
    // chunk id f = i*256 + tid; row r = f>>3; slot c = f&7 holds global chunk g = c ^ (r&7).
    const float* gA[4];
    int dstA[4];
#pragma unroll
    for (int i = 0; i < 4; ++i) {
        int f = i * 256 + tid;
        int r = f >> 3;
        int g = (f & 7) ^ (r & 7);
        gA[i] = Ax + (size_t)r * K_DIM + g * 4;
        dstA[i] = (i * 256 + wave * 64) * 4;  // wave-uniform chunk base (floats)
    }

    // B fragment source pointers: one per ni; per-iter offset kb*64 u16 folds to imm.
    const unsigned short* gB[4];
#pragma unroll
    for (int ni = 0; ni < 4; ++ni) {
        int rw = nb * BN + wn + ni * 16 + l16;
        gB[ni] = Wp + (size_t)rw * (NKBLK * 64) + quad * 8;
    }

    f32x4 accP[4][4];
    f32x4 accS[4][4];
#pragma unroll
    for (int i = 0; i < 4; ++i)
#pragma unroll
        for (int j = 0; j < 4; ++j) {
            accP[i][j] = (f32x4)(0.0f);
            accS[i][j] = (f32x4)(0.0f);
        }

    // ---- prologue: B(0) to regs, then A(0..3) to LDS ring; force B0,A0,A1 (A2,A3 stay in flight)
    u16x8v bab[4], bsg[4];
#pragma unroll
    for (int ni = 0; ni < 4; ++ni) {
        bab[ni] = *(const u16x8v*)(gB[ni]);
        bsg[ni] = *(const u16x8v*)(gB[ni] + 32);
    }
    asm volatile("" ::: "memory");  // keep B0 older than A issues
#pragma unroll
    for (int t = 0; t < 4; ++t)
#pragma unroll
        for (int i = 0; i < 4; ++i)
            gload_lds16(gA[i] + t * BK, &sA[t][dstA[i]]);
    asm volatile("s_waitcnt vmcnt(8)\n\ts_barrier" ::: "memory");

#pragma unroll
    for (int kb = 0; kb < NKBLK; ++kb) {
        const int cur = kb & 3;

        // ---- A fragments: ds_read fp32 + convert (abs->bf16 via cvt, sign via v_perm) ----
        bf16x8 aab[4], asg[4];
#pragma unroll
        for (int mi = 0; mi < 4; ++mi) {
            int m = wm + mi * 16 + l16;
            const float* rowp = &sA[cur][m * BK];
            int s0 = (2 * quad) ^ (m & 7);
            f32x4 f0 = *(const f32x4*)(rowp + s0 * 4);
            f32x4 f1 = *(const f32x4*)(rowp + (s0 ^ 1) * 4);
            u16x8v ab;
#pragma unroll
            for (int j = 0; j < 4; ++j) {
                ab[j]     = __builtin_bit_cast(unsigned short, (__bf16)__builtin_fabsf(f0[j]));
                ab[j + 4] = __builtin_bit_cast(unsigned short, (__bf16)__builtin_fabsf(f1[j]));
            }
            aab[mi] = __builtin_bit_cast(bf16x8, ab);
            u32x4v sg;
            sg[0] = sgnpk(f0[1], f0[0]);
            sg[1] = sgnpk(f0[3], f0[2]);
            sg[2] = sgnpk(f1[1], f1[0]);
            sg[3] = sgnpk(f1[3], f1[2]);
            asg[mi] = __builtin_bit_cast(bf16x8, sg);
        }

        // ---- MFMA (compiler inserts counted vmcnt for B regs; A(kb+3) DMA stays in flight) ----
#pragma unroll
        for (int mi = 0; mi < 4; ++mi)
#pragma unroll
            for (int ni = 0; ni < 4; ++ni) {
                accP[mi][ni] = __builtin_amdgcn_mfma_f32_16x16x32_bf16(
                    aab[mi], __builtin_bit_cast(bf16x8, bab[ni]), accP[mi][ni], 0, 0, 0);
                accS[mi][ni] = __builtin_amdgcn_mfma_f32_16x16x32_bf16(
                    asg[mi], __builtin_bit_cast(bf16x8, bsg[ni]), accS[mi][ni], 0, 0, 0);
            }

        if (kb + 1 < NKBLK) {
            // Next B tile (L2-hot): issue before the barrier for extra latency cover.
#pragma unroll
            for (int ni = 0; ni < 4; ++ni) {
                bab[ni] = *(const u16x8v*)(gB[ni] + (kb + 1) * 64);
                bsg[ni] = *(const u16x8v*)(gB[ni] + (kb + 1) * 64 + 32);
            }
            // All waves done reading sA[cur-ring] before next overwrite is issued.
            asm volatile("s_barrier" ::: "memory");
            if (kb + 4 < NKBLK) {
#pragma unroll
                for (int i = 0; i < 4; ++i)
                    gload_lds16(gA[i] + (kb + 4) * BK, &sA[(kb + 4) & 3][dstA[i]]);
            }
        }
    }

    // ---- epilogue: C/D layout col = l16, row = quad*4 + reg ----
#pragma unroll
    for (int ni = 0; ni < 4; ++ni) {
        int n   = nb * BN + wn + ni * 16 + l16;
        float b = bias[n];
#pragma unroll
        for (int mi = 0; mi < 4; ++mi) {
            int mbase = mb * BM + wm + mi * 16 + quad * 4;
#pragma unroll
            for (int r = 0; r < 4; ++r) {
                float p = accP[mi][ni][r];
                float s = accS[mi][ni][r];
                float v = (s > 0.0f) ? p : ((s < 0.0f) ? -p : 0.0f);
                out[(size_t)(mbase + r) * N_DIM + n] = v + b;
            }
        }
    }
}

extern "C" void kernel_launch(void* const* d_in, const int* in_sizes, int n_in,
                              void* d_out, int out_size, void* d_ws, size_t ws_size,
                              hipStream_t stream) {
    const float* x    = (const float*)d_in[0];
    const float* w    = (const float*)d_in[1];
    const float* bias = (const float*)d_in[2];
    float* out        = (float*)d_out;
    unsigned short* Wp = (unsigned short*)d_ws;  // 256 KB: [n][kblk][abs32|sgn32] bf16

    const int M = in_sizes[0] / K_DIM;  // 262144

    w_convert_kernel<<<dim3(64, 1, 1), dim3(256, 1, 1), 0, stream>>>(w, Wp);

    dim3 grid(N_DIM / BN, M / BM, 1);  // (2, 2048): nb fastest -> paired blocks share x slab in L2/L3
    dim3 block(256, 1, 1);
    lns_gemm_kernel<<<grid, block, 0, stream>>>(x, Wp, bias, out);
}

// Round 3
// 486.635 us; speedup vs baseline: 1.0569x; 1.0569x over previous
//
#include <hip/hip_runtime.h>
#include <stdint.h>

// LNSLinear inference: out[m,n] = sign(S[m,n]) * P[m,n] + bias[n]
//   P = |x| @ |w|^T (bf16), S = sign(x) @ sign(w)^T (exact, +-1 bf16)
// M = 262144, N = 256, K = 256.
// v4: block tile 64x128, 4 waves of 32x64 (2x2) -> acc 64 regs, cap 128 VGPR,
//     4 waves/SIMD, 2 blocks/CU.  (v3 bug: 32x64 waves with block=256 covered
//     only half the 128-row tile.)
//     A reg-staged: global->reg (8 fp32/thread), convert fp32->bf16 abs|sgn ONCE,
//     ds_write packed; row stride 144 B (bank distribution == linear).
//     B via global_load_lds (pre-swizzled source). MFMA operands all from LDS.
//     Steady waits: vmcnt(4) [A regs; B-DMA in flight] + vmcnt(2) [B-DMA done;
//     next A regs in flight] + 1 barrier/iter.  No vmcnt(0) in steady state.

#define K_DIM 256
#define N_DIM 256
#define BM 64
#define BN 128
#define BK 32
#define NKBLK 8   // K_DIM / BK
#define AROW 72   // u16 per sA row: abs 32 | sgn 32 | pad 8  (144 B)

typedef float f32x4 __attribute__((ext_vector_type(4)));
typedef __bf16 bf16x8 __attribute__((ext_vector_type(8)));
typedef unsigned short u16x4v __attribute__((ext_vector_type(4)));
typedef unsigned short u16x8v __attribute__((ext_vector_type(8)));
typedef unsigned int u32x4v __attribute__((ext_vector_type(4)));

// ---------- pre-kernel: W fp32 [N][K] -> ws bf16 rows [(n*8+kblk)][abs 32 | sgn 32] ----------
__global__ void w_convert_kernel(const float* __restrict__ W, unsigned short* __restrict__ Wp) {
    int t = blockIdx.x * 256 + threadIdx.x;  // 0..16383, each handles 4 k
    int n = t >> 6;
    int k = (t & 63) << 2;
    float4 v = *(const float4*)(W + (size_t)n * K_DIM + k);
    unsigned short* row = Wp + ((size_t)n * NKBLK + (k >> 5)) * 64;
    int pos = k & 31;
    float vv[4] = {v.x, v.y, v.z, v.w};
    u16x4v a, s;
#pragma unroll
    for (int j = 0; j < 4; ++j) {
        __bf16 h = (__bf16)__builtin_fabsf(vv[j]);
        a[j] = __builtin_bit_cast(unsigned short, h);
        unsigned int u = __float_as_uint(vv[j]);
        s[j] = (unsigned short)(0x3F80u | ((u >> 16) & 0x8000u));
    }
    *(u16x4v*)(row + pos) = a;
    *(u16x4v*)(row + 32 + pos) = s;
}

__device__ __forceinline__ void gload_lds16(const void* g, void* l) {
    __builtin_amdgcn_global_load_lds(
        (const __attribute__((address_space(1))) unsigned int*)g,
        (__attribute__((address_space(3))) unsigned int*)l, 16, 0, 0);
}

// Pack signs of two floats into one u32 of two bf16 (+1.0 / -1.0).
__device__ __forceinline__ unsigned int sgnpk(float hi, float lo) {
    return (__builtin_amdgcn_perm(__float_as_uint(hi), __float_as_uint(lo), 0x07000300u)
            & 0x80008000u) | 0x3F803F80u;
}

// ---------- main kernel ----------
__global__ __launch_bounds__(256, 4)
void lns_gemm_kernel(const float* __restrict__ X, const unsigned short* __restrict__ Wp,
                     const float* __restrict__ bias, float* __restrict__ out) {
    // sA: bf16-packed A tiles, row = 144 B (abs 64 B | sgn 64 B | pad 16 B)
    __shared__ __attribute__((aligned(16))) unsigned short sA[2][BM * AROW];  // 18 KB
    __shared__ __attribute__((aligned(16))) unsigned short sB[2][BN * 64];    // 32 KB

    const int tid  = threadIdx.x;
    const int lane = tid & 63;
    const int wave = tid >> 6;
    const int quad = lane >> 4;
    const int l16  = lane & 15;
    const int mb   = blockIdx.y;
    const int nb   = blockIdx.x;
    const int wm   = (wave >> 1) * 32;   // 2 waves down M (rows 0..63)
    const int wn   = (wave & 1) * 64;    // 2 waves across N

    // ---- A staging: 256 threads x 8 fp32 = 64 rows x 32 k ----
    const int ar = tid >> 2;             // row 0..63
    const int aq = tid & 3;              // k-quarter (8 floats)
    const float* gA = X + (size_t)(mb * BM + ar) * K_DIM + aq * 8;
    unsigned short* const wA0 = &sA[0][ar * AROW + aq * 8];
    unsigned short* const wA1 = &sA[1][ar * AROW + aq * 8];

    // ---- B staging: XOR-pre-swizzled global source, linear LDS dest ----
    const unsigned short* gB[4];
    int dstB[4];
#pragma unroll
    for (int i = 0; i < 4; ++i) {
        int f = i * 256 + tid;
        int r = f >> 3;
        int g = (f & 7) ^ (r & 7);
        gB[i] = Wp + ((size_t)(nb * BN + r)) * (NKBLK * 64) + g * 8;
        dstB[i] = (i * 256 + wave * 64) * 8;
    }

    f32x4 accP[2][4], accS[2][4];
#pragma unroll
    for (int i = 0; i < 2; ++i)
#pragma unroll
        for (int j = 0; j < 4; ++j) {
            accP[i][j] = (f32x4)(0.0f);
            accS[i][j] = (f32x4)(0.0f);
        }

    f32x4 ra[2];  // pending A tile (8 fp32 per thread)

#define LOAD_A(kbv) do { \
        const f32x4* _p = (const f32x4*)(gA + (kbv) * BK); \
        ra[0] = _p[0]; ra[1] = _p[1]; \
    } while (0)

#define CONV_WRITE_A(dst) do { \
        u16x8v _ab; \
        _Pragma("unroll") \
        for (int _j = 0; _j < 4; ++_j) { \
            _ab[_j]     = __builtin_bit_cast(unsigned short, (__bf16)__builtin_fabsf(ra[0][_j])); \
            _ab[_j + 4] = __builtin_bit_cast(unsigned short, (__bf16)__builtin_fabsf(ra[1][_j])); \
        } \
        u32x4v _sg; \
        _sg[0] = sgnpk(ra[0][1], ra[0][0]); _sg[1] = sgnpk(ra[0][3], ra[0][2]); \
        _sg[2] = sgnpk(ra[1][1], ra[1][0]); _sg[3] = sgnpk(ra[1][3], ra[1][2]); \
        *(u16x8v*)(dst)        = _ab; \
        *(u32x4v*)((dst) + 32) = _sg; \
    } while (0)

    // ---- prologue ----
    LOAD_A(0);                                             // A(0) x2
#pragma unroll
    for (int i = 0; i < 4; ++i) gload_lds16(gB[i], &sB[0][dstB[i]]);  // B(0) x4
    asm volatile("s_waitcnt vmcnt(4)" ::: "memory");       // A(0) regs done; B(0) in flight
    CONV_WRITE_A(wA0);
    LOAD_A(1);                                             // A(1) x2
#pragma unroll
    for (int i = 0; i < 4; ++i) gload_lds16(gB[i] + 64, &sB[1][dstB[i]]);  // B(1) x4
    // B(0) complete (A(1)+B(1)=6 stay in flight); my ds_writes visible; sync.
    asm volatile("s_waitcnt vmcnt(6) lgkmcnt(0)\n\ts_barrier" ::: "memory");

    // ---- main loop: entering kb, outstanding = [A(kb+1) x2] (+B(kb+1) x4 after top issue) ----
#pragma unroll
    for (int kb = 0; kb < NKBLK; ++kb) {
        const int cur = kb & 1;
        const int nxt = cur ^ 1;

        // B(kb+1) DMA at top of iter (target freed by end-of-(kb-1) barrier).
        if (kb >= 1 && kb + 1 < NKBLK) {
#pragma unroll
            for (int i = 0; i < 4; ++i)
                gload_lds16(gB[i] + (kb + 1) * 64, &sB[nxt][dstB[i]]);
        }

        // ---- fragments (all from LDS; no vmem deps) + MFMA ----
        bf16x8 aab[2], asg[2];
#pragma unroll
        for (int mi = 0; mi < 2; ++mi) {
            const unsigned short* rp = &sA[cur][(wm + mi * 16 + l16) * AROW + quad * 8];
            aab[mi] = __builtin_bit_cast(bf16x8, *(const u16x8v*)rp);
            asg[mi] = __builtin_bit_cast(bf16x8, *(const u16x8v*)(rp + 32));
        }
#pragma unroll
        for (int ni = 0; ni < 4; ++ni) {
            int r = wn + ni * 16 + l16;
            const unsigned short* rp = &sB[cur][r * 64];
            int sa = quad ^ (r & 7);
            bf16x8 bab = __builtin_bit_cast(bf16x8, *(const u16x8v*)(rp + sa * 8));
            bf16x8 bsg = __builtin_bit_cast(bf16x8, *(const u16x8v*)(rp + (sa ^ 4) * 8));
            accP[0][ni] = __builtin_amdgcn_mfma_f32_16x16x32_bf16(aab[0], bab, accP[0][ni], 0, 0, 0);
            accP[1][ni] = __builtin_amdgcn_mfma_f32_16x16x32_bf16(aab[1], bab, accP[1][ni], 0, 0, 0);
            accS[0][ni] = __builtin_amdgcn_mfma_f32_16x16x32_bf16(asg[0], bsg, accS[0][ni], 0, 0, 0);
            accS[1][ni] = __builtin_amdgcn_mfma_f32_16x16x32_bf16(asg[1], bsg, accS[1][ni], 0, 0, 0);
        }

        if (kb + 1 < NKBLK) {
            // A(kb+1) regs landed (issued last iter; MFMA phase covered the latency);
            // B(kb+1) DMA (4 ops, younger) stays in flight.
            asm volatile("s_waitcnt vmcnt(4)" ::: "memory");
            CONV_WRITE_A((kb & 1) ? wA0 : wA1);  // -> sA[nxt]
        }
        if (kb + 2 < NKBLK) LOAD_A(kb + 2);
        if (kb + 1 < NKBLK) {
            // B(kb+1) complete (A(kb+2) x2 stays in flight); writes visible; sync.
            if (kb + 2 < NKBLK)
                asm volatile("s_waitcnt vmcnt(2) lgkmcnt(0)\n\ts_barrier" ::: "memory");
            else
                asm volatile("s_waitcnt vmcnt(0) lgkmcnt(0)\n\ts_barrier" ::: "memory");
        }
    }

    // ---- epilogue: C/D layout col = l16, row = quad*4 + reg ----
#pragma unroll
    for (int ni = 0; ni < 4; ++ni) {
        int n   = nb * BN + wn + ni * 16 + l16;
        float b = bias[n];
#pragma unroll
        for (int mi = 0; mi < 2; ++mi) {
            int mbase = mb * BM + wm + mi * 16 + quad * 4;
#pragma unroll
            for (int r = 0; r < 4; ++r) {
                float p = accP[mi][ni][r];
                float s = accS[mi][ni][r];
                float v = (s > 0.0f) ? p : ((s < 0.0f) ? -p : 0.0f);
                out[(size_t)(mbase + r) * N_DIM + n] = v + b;
            }
        }
    }
}

extern "C" void kernel_launch(void* const* d_in, const int* in_sizes, int n_in,
                              void* d_out, int out_size, void* d_ws, size_t ws_size,
                              hipStream_t stream) {
    const float* x    = (const float*)d_in[0];
    const float* w    = (const float*)d_in[1];
    const float* bias = (const float*)d_in[2];
    float* out        = (float*)d_out;
    unsigned short* Wp = (unsigned short*)d_ws;  // 256 KB: [n][kblk][abs32|sgn32] bf16

    const int M = in_sizes[0] / K_DIM;  // 262144

    w_convert_kernel<<<dim3(64, 1, 1), dim3(256, 1, 1), 0, stream>>>(w, Wp);

    dim3 grid(N_DIM / BN, M / BM, 1);  // (2, 4096): nb fastest -> paired blocks share x slab in L2/L3
    dim3 block(256, 1, 1);
    lns_gemm_kernel<<<grid, block, 0, stream>>>(x, Wp, bias, out);
}